// Round 1
// baseline (265.390 us; speedup 1.0000x reference)
//
#include <hip/hip_runtime.h>

// Problem dims (fixed by reference): x shape (2,4,8,256,256) f32
#define WD 256
#define HT 256
#define DP 8
#define NBC 8
#define HW 65536       // HT*WD
#define DHW 524288     // DP*HW
#define NVOX 4194304   // NBC*DHW

// Full quadratic-interp refinement for one masked voxel; overwrites the
// 4 output scalars if the final 'valid' is true (defaults already written
// by phase1 otherwise). Math transcribed 1:1 from the reference; fp
// contraction off to track the numpy reference bit-closely.
__device__ void refine_write(const float* __restrict__ x,
                             float* __restrict__ out,
                             int idx) {
#pragma clang fp contract(off)
    const int w0 = idx & 255;
    const int h0 = (idx >> 8) & 255;
    const int d0 = (idx >> 16) & 7;
    const int bc = idx >> 19;
    int d = d0, h = h0, w = w0;
    bool valid = true;
    float shx = 0.f, shy = 0.f, shs = 0.f, gds = 0.f;
    const float* xb = x + (size_t)bc * DHW;
    for (int it = 0; it < 5; ++it) {
        int dcl = min(max(d, 1), DP - 2);
        int hcl = min(max(h, 1), HT - 2);
        int wcl = min(max(w, 1), WD - 2);
        const float* q = xb + dcl * HW + hcl * WD + wcl;
        float c000 = q[0];
        float pxm = q[-1],   pxp = q[1];
        float pym = q[-WD],  pyp = q[WD];
        float psm = q[-HW],  psp = q[HW];
        float gx = 0.5f * (pxp - pxm);
        float gy = 0.5f * (pyp - pym);
        float gs = 0.5f * (psp - psm);
        float dxx = pxp - 2.0f * c000 + pxm;
        float dyy = pyp - 2.0f * c000 + pym;
        float dss = psp - 2.0f * c000 + psm;
        float dxy = 0.25f * (q[WD + 1]  - q[WD - 1]  - q[-WD + 1]  + q[-WD - 1]);
        float dxs = 0.25f * (q[HW + 1]  - q[HW - 1]  - q[-HW + 1]  + q[-HW - 1]);
        float dys = 0.25f * (q[HW + WD] - q[HW - WD] - q[-HW + WD] + q[-HW - WD]);
        float r0 = -gx, r1 = -gy, r2 = -gs;
        float cf00 = dyy * dss - dys * dys;
        float cf01 = dxy * dss - dys * dxs;
        float cf02 = dxy * dys - dyy * dxs;
        float det = dxx * cf00 - dxy * cf01 + dxs * cf02;
        bool solved = fabsf(det) > 0.0f;
        float sdet = solved ? det : 1.0f;
        float sx = (r0 * cf00 - dxy * (r1 * dss - dys * r2) + dxs * (r1 * dys - dyy * r2)) / sdet;
        float sy = (dxx * (r1 * dss - dys * r2) - r0 * cf01 + dxs * (dxy * r2 - r1 * dxs)) / sdet;
        float ss = (dxx * (dyy * r2 - r1 * dys) - dxy * (dxy * r2 - r1 * dxs) + r0 * cf02) / sdet;
        valid = valid && solved;
        if (valid) {
            shx = sx; shy = sy; shs = ss;
            gds = gx * sx + gy * sy + gs * ss;
        } else {
            sx = 0.f; sy = 0.f; ss = 0.f;
        }
        int mvx = (valid && sx > 0.6f) ? 1 : ((valid && sx < -0.6f) ? -1 : 0);
        int nw = w + mvx;
        valid = valid && (nw >= 1) && (nw <= WD - 2);
        w = min(max(nw, 0), WD - 1);
        int mvy = (valid && sy > 0.6f) ? 1 : ((valid && sy < -0.6f) ? -1 : 0);
        int nh = h + mvy;
        valid = valid && (nh >= 1) && (nh <= HT - 2);
        h = min(max(nh, 0), HT - 1);
        int mvd = (valid && ss > 0.6f) ? 1 : ((valid && ss < -0.6f) ? -1 : 0);
        int nd = d + mvd;
        valid = valid && (nd >= 1) && (nd <= DP - 2);
        d = min(max(nd, 0), DP - 1);
        if (!valid) break;                    // state can no longer change
        if (mvx == 0 && mvy == 0 && mvd == 0) // fixed point: identical iterations follow
            break;
    }
    valid = valid && (fabsf(shx) <= 1.5f) && (fabsf(shy) <= 1.5f) && (fabsf(shs) <= 1.5f);
    if (!valid) return; // defaults (phase1) are the correct output

    size_t pos = (size_t)d0 * HW + (size_t)h0 * WD + (size_t)w0;
    float* cb = out + (size_t)(bc * 3) * DHW + pos;
    cb[0]         = (float)d + shs;
    cb[DHW]       = (float)w + shx;
    cb[2 * DHW]   = (float)h + shy;
    float corr = 0.5f * gds + 10.0f;
    float* yb = out + (size_t)NBC * 3 * DHW;
    yb[(size_t)bc * DHW + pos] = x[idx] + corr;
}

// Phase 1: one thread per 4 w-consecutive voxels. Writes default outputs,
// computes the 26-neighbor strict-max mask for interior voxels, and pushes
// maxima indices into the compaction list in d_ws.
__global__ __launch_bounds__(256) void phase1(const float* __restrict__ x,
                                              float* __restrict__ out,
                                              unsigned int* __restrict__ cnt,
                                              int* __restrict__ list,
                                              unsigned int cap) {
    int t = blockIdx.x * 256 + threadIdx.x;   // [0, NVOX/4)
    int lane = t & 63;
    int w0 = lane << 2;
    int h  = (t >> 6) & 255;
    int d  = (t >> 14) & 7;
    int bc = t >> 17;
    size_t pos = (size_t)d * HW + (size_t)h * WD + (size_t)w0;
    const float* xb = x + (size_t)bc * DHW;
    float4 c = *(const float4*)(xb + pos);

    // defaults: y = x ; coords = (d, w, h)
    float* yb = out + (size_t)NBC * 3 * DHW;
    *(float4*)(yb + (size_t)bc * DHW + pos) = c;
    float* cb = out + (size_t)(bc * 3) * DHW + pos;
    float fd = (float)d, fh = (float)h, fw = (float)w0;
    *(float4*)(cb)           = make_float4(fd, fd, fd, fd);
    *(float4*)(cb + DHW)     = make_float4(fw, fw + 1.f, fw + 2.f, fw + 3.f);
    *(float4*)(cb + 2 * DHW) = make_float4(fh, fh, fh, fh);

    if (d == 0 || d == DP - 1 || h == 0 || h == HT - 1) return; // border: never maxima

    const float NEG = -3.4e38f;
    float n0 = NEG, n1 = NEG, n2 = NEG, n3 = NEG;
    const float* rowc = xb + pos;
#pragma unroll
    for (int dd = -1; dd <= 1; ++dd) {
#pragma unroll
        for (int hh = -1; hh <= 1; ++hh) {
            float4 v;
            if (dd == 0 && hh == 0) v = c;
            else v = *(const float4*)(rowc + dd * HW + hh * WD);
            float L = __shfl_up(v.w, 1);   // lane-1's last elem = x[w0-1]
            float R = __shfl_down(v.x, 1); // lane+1's first elem = x[w0+4]
            if (dd == 0 && hh == 0) {
                // center row: exclude the center element itself
                n0 = fmaxf(n0, fmaxf(L,   v.y));
                n1 = fmaxf(n1, fmaxf(v.x, v.z));
                n2 = fmaxf(n2, fmaxf(v.y, v.w));
                n3 = fmaxf(n3, fmaxf(v.z, R));
            } else {
                n0 = fmaxf(n0, fmaxf(fmaxf(L,   v.x), v.y));
                n1 = fmaxf(n1, fmaxf(fmaxf(v.x, v.y), v.z));
                n2 = fmaxf(n2, fmaxf(fmaxf(v.y, v.z), v.w));
                n3 = fmaxf(n3, fmaxf(fmaxf(v.z, v.w), R));
            }
        }
    }
    bool m0 = (c.x > n0) && (w0 > 0);            // w=0 never a max (lane 0 L garbage is fine)
    bool m1 = (c.y > n1);
    bool m2 = (c.z > n2);
    bool m3 = (c.w > n3) && (w0 + 3 < WD - 1);   // w=255 never a max
    unsigned mbits = (m0 ? 1u : 0u) | (m1 ? 2u : 0u) | (m2 ? 4u : 0u) | (m3 ? 8u : 0u);
    if (!mbits) return;
    int vidx = (bc << 19) | (d << 16) | (h << 8) | w0;
    while (mbits) {
        int i = __ffs(mbits) - 1;
        mbits &= mbits - 1;
        if (cap > 0) {
            unsigned slot = atomicAdd(cnt, 1u);
            if (slot < cap) list[slot] = vidx + i;
            else refine_write(x, out, vidx + i);  // ws overflow fallback
        } else {
            refine_write(x, out, vidx + i);       // no usable ws
        }
    }
}

// Phase 2: grid-stride over the compacted maxima list.
__global__ __launch_bounds__(256) void phase2(const float* __restrict__ x,
                                              float* __restrict__ out,
                                              const unsigned int* __restrict__ cnt,
                                              const int* __restrict__ list,
                                              unsigned int cap) {
    unsigned n = *cnt;
    if (n > cap) n = cap;
    unsigned stride = gridDim.x * blockDim.x;
    for (unsigned i = blockIdx.x * blockDim.x + threadIdx.x; i < n; i += stride)
        refine_write(x, out, list[i]);
}

extern "C" void kernel_launch(void* const* d_in, const int* in_sizes, int n_in,
                              void* d_out, int out_size, void* d_ws, size_t ws_size,
                              hipStream_t stream) {
    const float* x = (const float*)d_in[0];
    float* out = (float*)d_out;
    if (ws_size >= 64) {
        unsigned int* cnt = (unsigned int*)d_ws;
        int* list = (int*)((char*)d_ws + 16);
        unsigned int cap = (unsigned int)((ws_size - 16) / 4);
        hipMemsetAsync(d_ws, 0, 16, stream);
        phase1<<<NVOX / 4 / 256, 256, 0, stream>>>(x, out, cnt, list, cap);
        phase2<<<512, 256, 0, stream>>>(x, out, cnt, list, cap);
    } else {
        // no usable scratch: inline refinement inside phase1 (slow path, still correct)
        phase1<<<NVOX / 4 / 256, 256, 0, stream>>>(x, out, nullptr, nullptr, 0u);
    }
}

// Round 2
// 90.843 us; speedup vs baseline: 2.9214x; 2.9214x over previous
//
#include <hip/hip_runtime.h>

// Problem dims (fixed by reference): x shape (2,4,8,256,256) f32
#define WD 256
#define HT 256
#define DP 8
#define NBC 8
#define HW 65536       // HT*WD
#define DHW 524288     // DP*HW
#define NVOX 4194304   // NBC*DHW

// Full quadratic-interp refinement for one masked voxel; overwrites the
// 4 output scalars if the final 'valid' is true (defaults already written
// by the caller otherwise). Math transcribed 1:1 from the reference; fp
// contraction off to track the numpy reference bit-closely.
__device__ void refine_write(const float* __restrict__ x,
                             float* __restrict__ out,
                             int idx) {
#pragma clang fp contract(off)
    const int w0 = idx & 255;
    const int h0 = (idx >> 8) & 255;
    const int d0 = (idx >> 16) & 7;
    const int bc = idx >> 19;
    int d = d0, h = h0, w = w0;
    bool valid = true;
    float shx = 0.f, shy = 0.f, shs = 0.f, gds = 0.f;
    const float* xb = x + (size_t)bc * DHW;
    for (int it = 0; it < 5; ++it) {
        int dcl = min(max(d, 1), DP - 2);
        int hcl = min(max(h, 1), HT - 2);
        int wcl = min(max(w, 1), WD - 2);
        const float* q = xb + dcl * HW + hcl * WD + wcl;
        float c000 = q[0];
        float pxm = q[-1],   pxp = q[1];
        float pym = q[-WD],  pyp = q[WD];
        float psm = q[-HW],  psp = q[HW];
        float gx = 0.5f * (pxp - pxm);
        float gy = 0.5f * (pyp - pym);
        float gs = 0.5f * (psp - psm);
        float dxx = pxp - 2.0f * c000 + pxm;
        float dyy = pyp - 2.0f * c000 + pym;
        float dss = psp - 2.0f * c000 + psm;
        float dxy = 0.25f * (q[WD + 1]  - q[WD - 1]  - q[-WD + 1]  + q[-WD - 1]);
        float dxs = 0.25f * (q[HW + 1]  - q[HW - 1]  - q[-HW + 1]  + q[-HW - 1]);
        float dys = 0.25f * (q[HW + WD] - q[HW - WD] - q[-HW + WD] + q[-HW - WD]);
        float r0 = -gx, r1 = -gy, r2 = -gs;
        float cf00 = dyy * dss - dys * dys;
        float cf01 = dxy * dss - dys * dxs;
        float cf02 = dxy * dys - dyy * dxs;
        float det = dxx * cf00 - dxy * cf01 + dxs * cf02;
        bool solved = fabsf(det) > 0.0f;
        float sdet = solved ? det : 1.0f;
        float sx = (r0 * cf00 - dxy * (r1 * dss - dys * r2) + dxs * (r1 * dys - dyy * r2)) / sdet;
        float sy = (dxx * (r1 * dss - dys * r2) - r0 * cf01 + dxs * (dxy * r2 - r1 * dxs)) / sdet;
        float ss = (dxx * (dyy * r2 - r1 * dys) - dxy * (dxy * r2 - r1 * dxs) + r0 * cf02) / sdet;
        valid = valid && solved;
        if (valid) {
            shx = sx; shy = sy; shs = ss;
            gds = gx * sx + gy * sy + gs * ss;
        } else {
            sx = 0.f; sy = 0.f; ss = 0.f;
        }
        int mvx = (valid && sx > 0.6f) ? 1 : ((valid && sx < -0.6f) ? -1 : 0);
        int nw = w + mvx;
        valid = valid && (nw >= 1) && (nw <= WD - 2);
        w = min(max(nw, 0), WD - 1);
        int mvy = (valid && sy > 0.6f) ? 1 : ((valid && sy < -0.6f) ? -1 : 0);
        int nh = h + mvy;
        valid = valid && (nh >= 1) && (nh <= HT - 2);
        h = min(max(nh, 0), HT - 1);
        int mvd = (valid && ss > 0.6f) ? 1 : ((valid && ss < -0.6f) ? -1 : 0);
        int nd = d + mvd;
        valid = valid && (nd >= 1) && (nd <= DP - 2);
        d = min(max(nd, 0), DP - 1);
        if (!valid) break;                    // state can no longer change
        if (mvx == 0 && mvy == 0 && mvd == 0) // fixed point: identical iterations follow
            break;
    }
    valid = valid && (fabsf(shx) <= 1.5f) && (fabsf(shy) <= 1.5f) && (fabsf(shs) <= 1.5f);
    if (!valid) return; // defaults are the correct output

    size_t pos = (size_t)d0 * HW + (size_t)h0 * WD + (size_t)w0;
    float* cb = out + (size_t)(bc * 3) * DHW + pos;
    cb[0]         = (float)d + shs;
    cb[DHW]       = (float)w + shx;
    cb[2 * DHW]   = (float)h + shy;
    float corr = 0.5f * gds + 10.0f;
    float* yb = out + (size_t)NBC * 3 * DHW;
    yb[(size_t)bc * DHW + pos] = x[idx] + corr;
}

// Single fused pass: one thread per 4 w-consecutive voxels. Writes default
// outputs, computes the 26-neighbor strict-max mask for interior voxels,
// and refines maxima inline (no atomics, no compaction — round-1 counters
// showed the single-address atomicAdd was the serializer: VALUBusy 1.8%,
// HBM 5.7%, dur 181us vs 13us BW floor).
__global__ __launch_bounds__(256) void fused(const float* __restrict__ x,
                                             float* __restrict__ out) {
    int t = blockIdx.x * 256 + threadIdx.x;   // [0, NVOX/4)
    int lane = t & 63;
    int w0 = lane << 2;
    int h  = (t >> 6) & 255;
    int d  = (t >> 14) & 7;
    int bc = t >> 17;
    size_t pos = (size_t)d * HW + (size_t)h * WD + (size_t)w0;
    const float* xb = x + (size_t)bc * DHW;
    float4 c = *(const float4*)(xb + pos);

    // defaults: y = x ; coords = (d, w, h)
    float* yb = out + (size_t)NBC * 3 * DHW;
    *(float4*)(yb + (size_t)bc * DHW + pos) = c;
    float* cb = out + (size_t)(bc * 3) * DHW + pos;
    float fd = (float)d, fh = (float)h, fw = (float)w0;
    *(float4*)(cb)           = make_float4(fd, fd, fd, fd);
    *(float4*)(cb + DHW)     = make_float4(fw, fw + 1.f, fw + 2.f, fw + 3.f);
    *(float4*)(cb + 2 * DHW) = make_float4(fh, fh, fh, fh);

    // border rows can never be strict maxima (edge-replicated padding);
    // d,h are wave-uniform (one wave == one row) so this exit keeps full
    // wave participation for the shuffles below.
    if (d == 0 || d == DP - 1 || h == 0 || h == HT - 1) return;

    const float NEG = -3.4e38f;
    float n0 = NEG, n1 = NEG, n2 = NEG, n3 = NEG;
    const float* rowc = xb + pos;
#pragma unroll
    for (int dd = -1; dd <= 1; ++dd) {
#pragma unroll
        for (int hh = -1; hh <= 1; ++hh) {
            float4 v;
            if (dd == 0 && hh == 0) v = c;
            else v = *(const float4*)(rowc + dd * HW + hh * WD);
            float L = __shfl_up(v.w, 1);   // lane-1's last elem = x[w0-1]
            float R = __shfl_down(v.x, 1); // lane+1's first elem = x[w0+4]
            if (dd == 0 && hh == 0) {
                // center row: exclude the center element itself
                n0 = fmaxf(n0, fmaxf(L,   v.y));
                n1 = fmaxf(n1, fmaxf(v.x, v.z));
                n2 = fmaxf(n2, fmaxf(v.y, v.w));
                n3 = fmaxf(n3, fmaxf(v.z, R));
            } else {
                n0 = fmaxf(n0, fmaxf(fmaxf(L,   v.x), v.y));
                n1 = fmaxf(n1, fmaxf(fmaxf(v.x, v.y), v.z));
                n2 = fmaxf(n2, fmaxf(fmaxf(v.y, v.z), v.w));
                n3 = fmaxf(n3, fmaxf(fmaxf(v.z, v.w), R));
            }
        }
    }
    bool m0 = (c.x > n0) && (w0 > 0);            // w=0 never a max (lane 0 L garbage is fine)
    bool m1 = (c.y > n1);
    bool m2 = (c.z > n2);
    bool m3 = (c.w > n3) && (w0 + 3 < WD - 1);   // w=255 never a max
    unsigned mbits = (m0 ? 1u : 0u) | (m1 ? 2u : 0u) | (m2 ? 4u : 0u) | (m3 ? 8u : 0u);
    if (!mbits) return;
    int vidx = (bc << 19) | (d << 16) | (h << 8) | w0;
    while (mbits) {
        int i = __ffs(mbits) - 1;
        mbits &= mbits - 1;
        refine_write(x, out, vidx + i);
    }
}

extern "C" void kernel_launch(void* const* d_in, const int* in_sizes, int n_in,
                              void* d_out, int out_size, void* d_ws, size_t ws_size,
                              hipStream_t stream) {
    const float* x = (const float*)d_in[0];
    float* out = (float*)d_out;
    (void)d_ws; (void)ws_size;
    fused<<<NVOX / 4 / 256, 256, 0, stream>>>(x, out);
}